// Round 21
// baseline (146.079 us; speedup 1.0000x reference)
//
#include <hip/hip_runtime.h>
#include <hip/hip_bf16.h>
#include <math.h>

#define NN 100000      // nodes
#define NE 1000000     // edges
#define NB 1024        // graphs
#define NCHUNK 6250    // NN/16
#define NRNG 256       // dst ranges
#define RANGE 391      // ceil(NN / NRNG)
#define NBK 512        // blocks for bucketing pass
#define EPB 1954       // edges per bucket-block: 512*1954 >= 1M
#define FEATB_BLKS 392 // 392*256 >= NN

typedef __attribute__((ext_vector_type(8))) short short8v;
typedef __attribute__((ext_vector_type(4))) float f32x4;

union frag16 { uint4 u; short8v s; };

static __device__ __forceinline__ float bf_lo(unsigned int u) {
    return __uint_as_float(u << 16);
}
static __device__ __forceinline__ float bf_hi(unsigned int u) {
    return __uint_as_float(u & 0xffff0000u);
}
static __device__ __forceinline__ unsigned int bf16_rne(float f) {
    unsigned int u = __float_as_uint(f);
    return (u + 0x7fffu + ((u >> 16) & 1u)) >> 16;
}
static __device__ __forceinline__ unsigned int pack_bf16(float a, float b) {
    return bf16_rne(a) | (bf16_rne(b) << 16);
}

// ---------------------------------------------------------------------------
// Fused: featb build (blocks < FEATB_BLKS) + edge bucket histogram (rest).
__global__ __launch_bounds__(256) void prep_kernel(
        const void* __restrict__ u, const void* __restrict__ v,
        unsigned char* __restrict__ featb,
        const int* __restrict__ n2g, int* __restrict__ gstart,
        const int* __restrict__ dst, int* __restrict__ bcnt) {
    __shared__ int sh[NRNG];
    const int tid = threadIdx.x;
    if (blockIdx.x < FEATB_BLKS) {
        // ---- featb path (+inlined bool-layout detection, fused boundary) ----
        int c;
        {
            const unsigned char* p = (const unsigned char*)u + tid * 4;
            c = (p[0] != 0) + (p[1] != 0) + (p[2] != 0) + (p[3] != 0);
        }
        #pragma unroll
        for (int off = 32; off > 0; off >>= 1) c += __shfl_xor(c, off);
        if (tid == 0) sh[0] = 0;
        __syncthreads();
        if ((tid & 63) == 0) atomicAdd(&sh[0], c);
        __syncthreads();
        bool is_u8 = (4 * sh[0] > 1024);   // u8: ~512 nonzero; i32: ~128
        int i = blockIdx.x * 256 + tid;
        if (i >= NN) return;
        unsigned char fu, fv;
        if (is_u8) {
            fu = ((const unsigned char*)u)[i] ? 1 : 0;
            fv = ((const unsigned char*)v)[i] ? 1 : 0;
        } else {
            fu = ((const int*)u)[i] ? 1 : 0;
            fv = ((const int*)v)[i] ? 1 : 0;
        }
        featb[i] = fu | (fv << 1);
        int g = n2g[i];
        if (i == 0) {
            gstart[g] = 0;
            gstart[NB] = NN;
        } else if (n2g[i - 1] != g) {
            gstart[g] = i;
        }
    } else {
        // ---- bcount path ----
        const int blk = blockIdx.x - FEATB_BLKS;
        sh[tid] = 0;
        __syncthreads();
        const int lo = blk * EPB, hi = min(NE, lo + EPB);
        for (int i = lo + tid; i < hi; i += 256)
            atomicAdd(&sh[dst[i] / RANGE], 1);
        __syncthreads();
        bcnt[tid * NBK + blk] = sh[tid];
    }
}

// Fused: per-bucket totals (blocks < NRNG) + W1/W2 fragment pre-pack (2 blocks).
__global__ __launch_bounds__(256) void wsum_kernel(
        const int* __restrict__ bcnt, int* __restrict__ btot,
        const float* __restrict__ W1, const float* __restrict__ W2,
        uint4* __restrict__ wpk1, uint4* __restrict__ wpk2) {
    __shared__ int s[4];
    const int tid = threadIdx.x;
    if (blockIdx.x < NRNG) {
        const int b = blockIdx.x;
        int c = bcnt[b * NBK + tid] + bcnt[b * NBK + 256 + tid];
        #pragma unroll
        for (int off = 32; off > 0; off >>= 1) c += __shfl_xor(c, off);
        if ((tid & 63) == 0) s[tid >> 6] = c;
        __syncthreads();
        if (tid == 0) btot[b] = s[0] + s[1] + s[2] + s[3];
    } else {
        if (tid >= 64) return;
        const float* W = (blockIdx.x == NRNG) ? W1 : W2;
        uint4* wpk = (blockIdx.x == NRNG) ? wpk1 : wpk2;
        const int lane = tid;
        const int bcol = lane & 15;
        const int krow = (lane >> 4) * 8;
        #pragma unroll
        for (int n = 0; n < 4; ++n) {
            #pragma unroll
            for (int t = 0; t < 2; ++t) {
                unsigned int p[4];
                #pragma unroll
                for (int jj = 0; jj < 4; ++jj) {
                    int k0 = t * 32 + krow + 2 * jj;
                    float w0 = W[(size_t)k0 * 64 + n * 16 + bcol];
                    float w1 = W[(size_t)(k0 + 1) * 64 + n * 16 + bcol];
                    p[jj] = pack_bf16(w0, w1);
                }
                wpk[(n * 2 + t) * 64 + lane] = make_uint4(p[0], p[1], p[2], p[3]);
            }
        }
    }
}

// stage 2 (fused): bucket-total scan (block 0 writes bstart) + per-bucket
// exclusive scan of the 512 per-block counts -> bbase.
__global__ __launch_bounds__(256) void bbase_kernel(const int* __restrict__ bcnt,
                                                    const int* __restrict__ btot,
                                                    int* __restrict__ bstart,
                                                    int* __restrict__ bbase) {
    __shared__ int s[256];
    const int b = blockIdx.x, tid = threadIdx.x;
    int v = btot[tid];
    s[tid] = v;
    __syncthreads();
    for (int off = 1; off < 256; off <<= 1) {
        int t = (tid >= off) ? s[tid - off] : 0;
        __syncthreads();
        s[tid] += t;
        __syncthreads();
    }
    if (b == 0) {
        bstart[tid] = s[tid] - v;
        if (tid == 255) bstart[NRNG] = s[tid];
    }
    const int exb = s[b] - btot[b];            // exclusive start of bucket b
    __syncthreads();
    int2 c = ((const int2*)(bcnt + b * NBK))[tid];
    int lsum = c.x + c.y;
    s[tid] = lsum;
    __syncthreads();
    for (int off = 1; off < 256; off <<= 1) {
        int t = (tid >= off) ? s[tid - off] : 0;
        __syncthreads();
        s[tid] += t;
        __syncthreads();
    }
    int run = exb + s[tid] - lsum;
    ((int2*)(bbase + b * NBK))[tid] = make_int2(run, run + c.x);
}

__global__ __launch_bounds__(256) void bwrite_kernel(const int* __restrict__ src,
                                                     const int* __restrict__ dst,
                                                     const int* __restrict__ bbase,
                                                     unsigned int* __restrict__ ebuck, int e) {
    __shared__ int cur[NRNG];
    const int blk = blockIdx.x;
    cur[threadIdx.x] = bbase[threadIdx.x * NBK + blk];
    __syncthreads();
    const int lo = blk * EPB, hi = min(e, lo + EPB);
    for (int i = lo + threadIdx.x; i < hi; i += 256) {
        int d = dst[i];
        int b = d / RANGE;
        int dloc = d - b * RANGE;                  // < 391 < 2^9
        int pos = atomicAdd(&cur[b], 1);
        ebuck[pos] = (unsigned int)src[i] | ((unsigned int)dloc << 17);
    }
}

// ---------------- fused CSR build + layer-0 node transform ------------------
__global__ __launch_bounds__(256) void build_kernel(
        const unsigned int* __restrict__ ebuck, const int* __restrict__ bstart,
        const unsigned char* __restrict__ featb,
        const float* __restrict__ W0, const float* __restrict__ b0,
        const float* __restrict__ epsp,
        int* __restrict__ rowptr, int* __restrict__ esrc,
        unsigned short* __restrict__ hout) {
    __shared__ unsigned long long hloc[RANGE];     // 3128 B
    __shared__ int cur[RANGE];                     // 1564 B
    __shared__ int sscan[256];
    __shared__ float w0s[128];
    __shared__ float b0s[64];
    const int r = blockIdx.x, tid = threadIdx.x;
    const int nlo = r * RANGE;
    const int nr = min(NN, nlo + RANGE) - nlo;
    for (int i = tid; i < nr; i += 256) hloc[i] = 0ull;
    if (tid < 128) w0s[tid] = W0[tid];
    if (tid >= 128 && tid < 192) b0s[tid - 128] = b0[tid - 128];
    __syncthreads();
    const int elo = bstart[r], ehi = bstart[r + 1];
    // pass 1: LDS histogram
    for (int i = elo + tid; i < ehi; i += 256) {
        unsigned int u = ebuck[i];
        unsigned char f = featb[u & 0x1FFFFu];
        unsigned long long inc = 1ull
            | ((unsigned long long)(f & 1) << 21)
            | ((unsigned long long)(f >> 1) << 42);
        atomicAdd(&hloc[u >> 17], inc);
    }
    __syncthreads();
    // in-LDS exclusive scan of degrees (2 slots per thread)
    const int base = tid * 2;
    int ldeg[2];
    int lsum = 0;
    #pragma unroll
    for (int j = 0; j < 2; ++j) {
        int i = base + j;
        ldeg[j] = (i < nr) ? (int)(hloc[i] & 0x1FFFFFull) : 0;
        lsum += ldeg[j];
    }
    sscan[tid] = lsum;
    __syncthreads();
    for (int off = 1; off < 256; off <<= 1) {
        int t = (tid >= off) ? sscan[tid - off] : 0;
        __syncthreads();
        sscan[tid] += t;
        __syncthreads();
    }
    int run = elo + sscan[tid] - lsum;
    #pragma unroll
    for (int j = 0; j < 2; ++j) {
        int i = base + j;
        if (i < nr) {
            rowptr[nlo + i] = run;
            cur[i] = run;
            run += ldeg[j];
        }
    }
    if (r == NRNG - 1 && tid == 0) rowptr[NN] = bstart[NRNG];
    __syncthreads();
    // pass 2: scatter via LDS cursors
    for (int i = elo + tid; i < ehi; i += 256) {
        unsigned int u = ebuck[i];
        int pos = atomicAdd(&cur[u >> 17], 1);
        esrc[pos] = (int)(u & 0x1FFFFu);
    }
    // layer-0 node transform (hloc unchanged since hist sync)
    const float e = 1.0f + epsp[0];
    for (int idx = tid; idx < nr * 8; idx += 256) {
        int i = idx >> 3, oct = idx & 7;
        unsigned long long hv = hloc[i];
        float cu = (float)((hv >> 21) & 0x1FFFFFull);
        float cv = (float)(hv >> 42);
        unsigned char f = featb[nlo + i];
        float z0 = fmaf(e, (float)(f & 1), cu);
        float z1 = fmaf(e, (float)(f >> 1), cv);
        unsigned int p[4];
        #pragma unroll
        for (int k = 0; k < 4; ++k) {
            int c0 = oct * 8 + 2 * k;
            float o0 = fmaxf(fmaf(z0, w0s[c0],     fmaf(z1, w0s[64 + c0],     b0s[c0])),     0.0f);
            float o1 = fmaxf(fmaf(z0, w0s[c0 + 1], fmaf(z1, w0s[64 + c0 + 1], b0s[c0 + 1])), 0.0f);
            p[k] = pack_bf16(o0, o1);
        }
        ((uint4*)(hout + (size_t)(nlo + i) * 64))[oct] = make_uint4(p[0], p[1], p[2], p[3]);
    }
}

// ---------------- layers 1/2: prefetch+shfl gather + MFMA GEMV -------------
__global__ __launch_bounds__(256) void gin_layer_kernel(
        const int* __restrict__ rowptr, const int* __restrict__ esrc,
        const unsigned short* __restrict__ hin,
        const uint4* __restrict__ wpk, const float* __restrict__ b,
        const float* __restrict__ epsp, unsigned short* __restrict__ hout) {
    __shared__ __align__(16) unsigned char zall[4][2048];   // per-wave z[16][64] bf16
    const int tid = threadIdx.x;
    const int lane = tid & 63;
    const int g = lane >> 3;            // node group 0..7
    const int sub = lane & 7;           // 16B chunk (cols 8*sub..8*sub+7)
    unsigned char* zw = &zall[tid >> 6][0];
    const float ep = 1.0f + epsp[0];

    // preload B fragments from pre-packed global (8 x uint4, L2-hot)
    const int bcol = (lane & 15);
    frag16 Bf[4][2];
    #pragma unroll
    for (int n = 0; n < 4; ++n) {
        #pragma unroll
        for (int t = 0; t < 2; ++t)
            Bf[n][t].u = wpk[(n * 2 + t) * 64 + lane];
    }
    float bj[4];
    #pragma unroll
    for (int n = 0; n < 4; ++n) bj[n] = b[n * 16 + bcol];

    const int wid = (blockIdx.x * blockDim.x + tid) >> 6;
    const int nwaves = (gridDim.x * blockDim.x) >> 6;

    for (int chunk = wid; chunk < NCHUNK; chunk += nwaves) {
        const int cbase_n = chunk * 16;
        // ---- Phase A: two batches of 8 nodes ----
        #pragma unroll
        for (int b8 = 0; b8 < 2; ++b8) {
            int node = cbase_n + b8 * 8 + g;
            int e0 = rowptr[node], e1 = rowptr[node + 1];
            int deg = e1 - e0;
            uint4 ov = ((const uint4*)(hin + (size_t)node * 64))[sub];
            float acc[8];
            #pragma unroll
            for (int c = 0; c < 8; ++c) acc[c] = 0.0f;
            int md = deg;
            md = max(md, __shfl_xor(md, 8));
            md = max(md, __shfl_xor(md, 16));
            md = max(md, __shfl_xor(md, 32));
            // 8 edge indices per group fetched in ONE wave-load, consumed
            // via shfl -> gathers have no serial esrc dependency.
            for (int tb = 0; tb < md; tb += 8) {
                int ei = max(min(e0 + tb + sub, e1 - 1), 0);
                int sidx = esrc[ei];
                #pragma unroll 4
                for (int tt = 0; tt < 8; ++tt) {
                    int t = tb + tt;
                    int s_ = __shfl(sidx, (lane & 56) + tt);
                    bool act = (t < deg);
                    int s = act ? s_ : node;        // masked: own row (L1-hot)
                    uint4 v = ((const uint4*)(hin + (size_t)s * 64))[sub];
                    float m = act ? 1.0f : 0.0f;
                    acc[0] = fmaf(m, bf_lo(v.x), acc[0]);
                    acc[1] = fmaf(m, bf_hi(v.x), acc[1]);
                    acc[2] = fmaf(m, bf_lo(v.y), acc[2]);
                    acc[3] = fmaf(m, bf_hi(v.y), acc[3]);
                    acc[4] = fmaf(m, bf_lo(v.z), acc[4]);
                    acc[5] = fmaf(m, bf_hi(v.z), acc[5]);
                    acc[6] = fmaf(m, bf_lo(v.w), acc[6]);
                    acc[7] = fmaf(m, bf_hi(v.w), acc[7]);
                }
            }
            acc[0] = fmaf(ep, bf_lo(ov.x), acc[0]);
            acc[1] = fmaf(ep, bf_hi(ov.x), acc[1]);
            acc[2] = fmaf(ep, bf_lo(ov.y), acc[2]);
            acc[3] = fmaf(ep, bf_hi(ov.y), acc[3]);
            acc[4] = fmaf(ep, bf_lo(ov.z), acc[4]);
            acc[5] = fmaf(ep, bf_hi(ov.z), acc[5]);
            acc[6] = fmaf(ep, bf_lo(ov.w), acc[6]);
            acc[7] = fmaf(ep, bf_hi(ov.w), acc[7]);
            uint4 pk = make_uint4(pack_bf16(acc[0], acc[1]), pack_bf16(acc[2], acc[3]),
                                  pack_bf16(acc[4], acc[5]), pack_bf16(acc[6], acc[7]));
            int row = b8 * 8 + g;
            *(uint4*)&zw[row * 128 + ((sub ^ g) << 4)] = pk;
        }
        // ---- Phase B: z[16][64] @ W[64][64] via MFMA ----
        const int arow = lane & 15;
        const int hi = lane >> 4;
        frag16 a0, a1;
        a0.u = *(const uint4*)&zw[arow * 128 + (((hi + 0) ^ (lane & 7)) << 4)];
        a1.u = *(const uint4*)&zw[arow * 128 + (((hi + 4) ^ (lane & 7)) << 4)];
        #pragma unroll
        for (int n = 0; n < 4; ++n) {
            f32x4 c = {bj[n], bj[n], bj[n], bj[n]};
            c = __builtin_amdgcn_mfma_f32_16x16x32_bf16(a0.s, Bf[n][0].s, c, 0, 0, 0);
            c = __builtin_amdgcn_mfma_f32_16x16x32_bf16(a1.s, Bf[n][1].s, c, 0, 0, 0);
            #pragma unroll
            for (int q = 0; q < 4; ++q) {
                int rr = hi * 4 + q;
                float v = fmaxf(c[q], 0.0f);
                hout[(size_t)(cbase_n + rr) * 64 + n * 16 + bcol] =
                    (unsigned short)bf16_rne(v);
            }
        }
    }
}

// ---------------- fused mean-pool + scorer: one wave per graph ------------
__global__ __launch_bounds__(256) void pool_scorer_kernel(
        const unsigned short* __restrict__ h, const int* __restrict__ gstart,
        const float* __restrict__ Ws1, const float* __restrict__ bs1,
        const float* __restrict__ Ws2, const float* __restrict__ bs2,
        float* __restrict__ out) {
    int g = blockIdx.x * 4 + (threadIdx.x >> 6);
    int lane = threadIdx.x & 63;
    if (g >= NB) return;
    int s0 = gstart[g], s1 = gstart[g + 1];
    float a0 = 0.0f, a1 = 0.0f, a2 = 0.0f, a3 = 0.0f;
    int i = s0;
    for (; i + 4 <= s1; i += 4) {
        a0 += __uint_as_float((unsigned int)h[(size_t)(i    ) * 64 + lane] << 16);
        a1 += __uint_as_float((unsigned int)h[(size_t)(i + 1) * 64 + lane] << 16);
        a2 += __uint_as_float((unsigned int)h[(size_t)(i + 2) * 64 + lane] << 16);
        a3 += __uint_as_float((unsigned int)h[(size_t)(i + 3) * 64 + lane] << 16);
    }
    for (; i < s1; ++i)
        a0 += __uint_as_float((unsigned int)h[(size_t)i * 64 + lane] << 16);
    float mean = ((a0 + a1) + (a2 + a3)) / fmaxf((float)(s1 - s0), 1.0f);
    float o = bs1[lane];
    #pragma unroll 8
    for (int k = 0; k < 64; ++k)
        o = fmaf(__shfl(mean, k), Ws1[(size_t)k * 64 + lane], o);
    float z = fmaxf(o, 0.0f) * Ws2[lane];
    #pragma unroll
    for (int off = 32; off > 0; off >>= 1) z += __shfl_xor(z, off);
    if (lane == 0) out[g] = 1.0f / (1.0f + expf(-(z + bs2[0])));
}

extern "C" void kernel_launch(void* const* d_in, const int* in_sizes, int n_in,
                              void* d_out, int out_size, void* d_ws, size_t ws_size,
                              hipStream_t stream) {
    const void*  u_flag = d_in[0];
    const void*  v_flag = d_in[1];
    const int*   src    = (const int*)d_in[2];
    const int*   dst    = (const int*)d_in[3];
    const int*   n2g    = (const int*)d_in[4];
    const float* W0     = (const float*)d_in[5];
    const float* b0     = (const float*)d_in[6];
    const float* eps0   = (const float*)d_in[7];
    const float* W1     = (const float*)d_in[8];
    const float* b1     = (const float*)d_in[9];
    const float* eps1   = (const float*)d_in[10];
    const float* W2     = (const float*)d_in[11];
    const float* b2     = (const float*)d_in[12];
    const float* eps2   = (const float*)d_in[13];
    const float* Ws1    = (const float*)d_in[14];
    const float* bs1    = (const float*)d_in[15];
    const float* Ws2    = (const float*)d_in[16];
    const float* bs2    = (const float*)d_in[17];
    float* out = (float*)d_out;

    // ---- workspace layout (int = 4-byte units), non-overlapping ----
    int*    ws     = (int*)d_ws;
    int*    rowptr = ws;                                    // [0,        100001)
    int*    gstart = ws + 100008;                           // [100008,   101033)
    unsigned char* featb = (unsigned char*)(ws + 101036);   // [101036,   126036) 100000 B
    unsigned short* h_a = (unsigned short*)(ws + 126036);   // [126036,   3326036)
    unsigned short* h_b = (unsigned short*)(ws + 3326036);  // [3326036,  6526036)
    int*    esrc   = ws + 6526036;                          // [6526036,  7526036)
    int*    bcnt   = ws + 7526036;                          // [7526036,  7657108) 131072
    int*    bbase  = ws + 7657108;                          // [7657108,  7788180) 131072
    int*    bstart = ws + 7788180;                          // [7788180,  7788437) 257
    int*    btot   = ws + 7788440;                          // [7788440,  7788696) 256
    unsigned int* ebuck = (unsigned int*)(ws + 7788696);    // [7788696,  8788696) NE
    uint4*  wpk1   = (uint4*)(ws + 8788696);                // [8788696,  8790744) 512 uint4
    uint4*  wpk2   = (uint4*)(ws + 8790744);                // [8790744,  8792792)

    const int B256 = 256;

    // fused featb + bucket histogram
    prep_kernel<<<FEATB_BLKS + NBK, B256, 0, stream>>>(u_flag, v_flag, featb,
                                                       n2g, gstart, dst, bcnt);

    // fused bucket totals + W fragment pre-pack
    wsum_kernel<<<NRNG + 2, B256, 0, stream>>>(bcnt, btot, W1, W2, wpk1, wpk2);

    // bucket scan + edge bucketing
    bbase_kernel<<<NRNG, B256, 0, stream>>>(bcnt, btot, bstart, bbase);
    bwrite_kernel<<<NBK, B256, 0, stream>>>(src, dst, bbase, ebuck, NE);

    // fused CSR build + layer-0 transform
    build_kernel<<<NRNG, B256, 0, stream>>>(ebuck, bstart, featb, W0, b0, eps0,
                                            rowptr, esrc, h_a);

    // layers 1/2 (1563 blocks = 6252 waves -> ~1 chunk per wave)
    gin_layer_kernel<<<1563, 256, 0, stream>>>(rowptr, esrc, h_a, wpk1, b1, eps1, h_b);
    gin_layer_kernel<<<1563, 256, 0, stream>>>(rowptr, esrc, h_b, wpk2, b2, eps2, h_a);

    // fused mean-pool + scorer
    pool_scorer_kernel<<<NB / 4, 256, 0, stream>>>(h_a, gstart, Ws1, bs1, Ws2, bs2, out);
}

// Round 22
// 131.743 us; speedup vs baseline: 1.1088x; 1.1088x over previous
//
#include <hip/hip_runtime.h>
#include <hip/hip_bf16.h>
#include <math.h>

#define NN 100000      // nodes
#define NE 1000000     // edges
#define NB 1024        // graphs
#define NCHUNK 6250    // NN/16
#define NRNG 256       // dst ranges
#define RANGE 391      // ceil(NN / NRNG)
#define NBK 512        // blocks for bucketing pass
#define EPB 1954       // edges per bucket-block: 512*1954 >= 1M
#define FEATB_BLKS 392 // 392*256 >= NN

typedef __attribute__((ext_vector_type(8))) short short8v;
typedef __attribute__((ext_vector_type(4))) float f32x4;

union frag16 { uint4 u; short8v s; };

static __device__ __forceinline__ float bf_lo(unsigned int u) {
    return __uint_as_float(u << 16);
}
static __device__ __forceinline__ float bf_hi(unsigned int u) {
    return __uint_as_float(u & 0xffff0000u);
}
static __device__ __forceinline__ unsigned int bf16_rne(float f) {
    unsigned int u = __float_as_uint(f);
    return (u + 0x7fffu + ((u >> 16) & 1u)) >> 16;
}
static __device__ __forceinline__ unsigned int pack_bf16(float a, float b) {
    return bf16_rne(a) | (bf16_rne(b) << 16);
}

// ---------------------------------------------------------------------------
// Fused: featb build (blocks < FEATB_BLKS) + edge bucket histogram (rest).
__global__ __launch_bounds__(256) void prep_kernel(
        const void* __restrict__ u, const void* __restrict__ v,
        unsigned char* __restrict__ featb,
        const int* __restrict__ n2g, int* __restrict__ gstart,
        const int* __restrict__ dst, int* __restrict__ bcnt) {
    __shared__ int sh[NRNG];
    const int tid = threadIdx.x;
    if (blockIdx.x < FEATB_BLKS) {
        // ---- featb path (+inlined bool-layout detection, fused boundary) ----
        int c;
        {
            const unsigned char* p = (const unsigned char*)u + tid * 4;
            c = (p[0] != 0) + (p[1] != 0) + (p[2] != 0) + (p[3] != 0);
        }
        #pragma unroll
        for (int off = 32; off > 0; off >>= 1) c += __shfl_xor(c, off);
        if (tid == 0) sh[0] = 0;
        __syncthreads();
        if ((tid & 63) == 0) atomicAdd(&sh[0], c);
        __syncthreads();
        bool is_u8 = (4 * sh[0] > 1024);   // u8: ~512 nonzero; i32: ~128
        int i = blockIdx.x * 256 + tid;
        if (i >= NN) return;
        unsigned char fu, fv;
        if (is_u8) {
            fu = ((const unsigned char*)u)[i] ? 1 : 0;
            fv = ((const unsigned char*)v)[i] ? 1 : 0;
        } else {
            fu = ((const int*)u)[i] ? 1 : 0;
            fv = ((const int*)v)[i] ? 1 : 0;
        }
        featb[i] = fu | (fv << 1);
        int g = n2g[i];
        if (i == 0) {
            gstart[g] = 0;
            gstart[NB] = NN;
        } else if (n2g[i - 1] != g) {
            gstart[g] = i;
        }
    } else {
        // ---- bcount path ----
        const int blk = blockIdx.x - FEATB_BLKS;
        sh[tid] = 0;
        __syncthreads();
        const int lo = blk * EPB, hi = min(NE, lo + EPB);
        for (int i = lo + tid; i < hi; i += 256)
            atomicAdd(&sh[dst[i] / RANGE], 1);
        __syncthreads();
        bcnt[tid * NBK + blk] = sh[tid];
    }
}

// Fused: per-bucket totals (blocks < NRNG) + W1/W2 fragment pre-pack (2 blocks).
__global__ __launch_bounds__(256) void wsum_kernel(
        const int* __restrict__ bcnt, int* __restrict__ btot,
        const float* __restrict__ W1, const float* __restrict__ W2,
        uint4* __restrict__ wpk1, uint4* __restrict__ wpk2) {
    __shared__ int s[4];
    const int tid = threadIdx.x;
    if (blockIdx.x < NRNG) {
        const int b = blockIdx.x;
        int c = bcnt[b * NBK + tid] + bcnt[b * NBK + 256 + tid];
        #pragma unroll
        for (int off = 32; off > 0; off >>= 1) c += __shfl_xor(c, off);
        if ((tid & 63) == 0) s[tid >> 6] = c;
        __syncthreads();
        if (tid == 0) btot[b] = s[0] + s[1] + s[2] + s[3];
    } else {
        if (tid >= 64) return;
        const float* W = (blockIdx.x == NRNG) ? W1 : W2;
        uint4* wpk = (blockIdx.x == NRNG) ? wpk1 : wpk2;
        const int lane = tid;
        const int bcol = lane & 15;
        const int krow = (lane >> 4) * 8;
        #pragma unroll
        for (int n = 0; n < 4; ++n) {
            #pragma unroll
            for (int t = 0; t < 2; ++t) {
                unsigned int p[4];
                #pragma unroll
                for (int jj = 0; jj < 4; ++jj) {
                    int k0 = t * 32 + krow + 2 * jj;
                    float w0 = W[(size_t)k0 * 64 + n * 16 + bcol];
                    float w1 = W[(size_t)(k0 + 1) * 64 + n * 16 + bcol];
                    p[jj] = pack_bf16(w0, w1);
                }
                wpk[(n * 2 + t) * 64 + lane] = make_uint4(p[0], p[1], p[2], p[3]);
            }
        }
    }
}

// stage 2 (fused): bucket-total scan (block 0 writes bstart) + per-bucket
// exclusive scan of the 512 per-block counts -> bbase.
__global__ __launch_bounds__(256) void bbase_kernel(const int* __restrict__ bcnt,
                                                    const int* __restrict__ btot,
                                                    int* __restrict__ bstart,
                                                    int* __restrict__ bbase) {
    __shared__ int s[256];
    const int b = blockIdx.x, tid = threadIdx.x;
    int v = btot[tid];
    s[tid] = v;
    __syncthreads();
    for (int off = 1; off < 256; off <<= 1) {
        int t = (tid >= off) ? s[tid - off] : 0;
        __syncthreads();
        s[tid] += t;
        __syncthreads();
    }
    if (b == 0) {
        bstart[tid] = s[tid] - v;
        if (tid == 255) bstart[NRNG] = s[tid];
    }
    const int exb = s[b] - btot[b];            // exclusive start of bucket b
    __syncthreads();
    int2 c = ((const int2*)(bcnt + b * NBK))[tid];
    int lsum = c.x + c.y;
    s[tid] = lsum;
    __syncthreads();
    for (int off = 1; off < 256; off <<= 1) {
        int t = (tid >= off) ? s[tid - off] : 0;
        __syncthreads();
        s[tid] += t;
        __syncthreads();
    }
    int run = exb + s[tid] - lsum;
    ((int2*)(bbase + b * NBK))[tid] = make_int2(run, run + c.x);
}

__global__ __launch_bounds__(256) void bwrite_kernel(const int* __restrict__ src,
                                                     const int* __restrict__ dst,
                                                     const int* __restrict__ bbase,
                                                     unsigned int* __restrict__ ebuck, int e) {
    __shared__ int cur[NRNG];
    const int blk = blockIdx.x;
    cur[threadIdx.x] = bbase[threadIdx.x * NBK + blk];
    __syncthreads();
    const int lo = blk * EPB, hi = min(e, lo + EPB);
    for (int i = lo + threadIdx.x; i < hi; i += 256) {
        int d = dst[i];
        int b = d / RANGE;
        int dloc = d - b * RANGE;                  // < 391 < 2^9
        int pos = atomicAdd(&cur[b], 1);
        ebuck[pos] = (unsigned int)src[i] | ((unsigned int)dloc << 17);
    }
}

// ---------------- fused CSR build + layer-0 node transform ------------------
__global__ __launch_bounds__(256) void build_kernel(
        const unsigned int* __restrict__ ebuck, const int* __restrict__ bstart,
        const unsigned char* __restrict__ featb,
        const float* __restrict__ W0, const float* __restrict__ b0,
        const float* __restrict__ epsp,
        int* __restrict__ rowptr, int* __restrict__ esrc,
        unsigned short* __restrict__ hout) {
    __shared__ unsigned long long hloc[RANGE];     // 3128 B
    __shared__ int cur[RANGE];                     // 1564 B
    __shared__ int sscan[256];
    __shared__ float w0s[128];
    __shared__ float b0s[64];
    const int r = blockIdx.x, tid = threadIdx.x;
    const int nlo = r * RANGE;
    const int nr = min(NN, nlo + RANGE) - nlo;
    for (int i = tid; i < nr; i += 256) hloc[i] = 0ull;
    if (tid < 128) w0s[tid] = W0[tid];
    if (tid >= 128 && tid < 192) b0s[tid - 128] = b0[tid - 128];
    __syncthreads();
    const int elo = bstart[r], ehi = bstart[r + 1];
    // pass 1: LDS histogram
    for (int i = elo + tid; i < ehi; i += 256) {
        unsigned int u = ebuck[i];
        unsigned char f = featb[u & 0x1FFFFu];
        unsigned long long inc = 1ull
            | ((unsigned long long)(f & 1) << 21)
            | ((unsigned long long)(f >> 1) << 42);
        atomicAdd(&hloc[u >> 17], inc);
    }
    __syncthreads();
    // in-LDS exclusive scan of degrees (2 slots per thread)
    const int base = tid * 2;
    int ldeg[2];
    int lsum = 0;
    #pragma unroll
    for (int j = 0; j < 2; ++j) {
        int i = base + j;
        ldeg[j] = (i < nr) ? (int)(hloc[i] & 0x1FFFFFull) : 0;
        lsum += ldeg[j];
    }
    sscan[tid] = lsum;
    __syncthreads();
    for (int off = 1; off < 256; off <<= 1) {
        int t = (tid >= off) ? sscan[tid - off] : 0;
        __syncthreads();
        sscan[tid] += t;
        __syncthreads();
    }
    int run = elo + sscan[tid] - lsum;
    #pragma unroll
    for (int j = 0; j < 2; ++j) {
        int i = base + j;
        if (i < nr) {
            rowptr[nlo + i] = run;
            cur[i] = run;
            run += ldeg[j];
        }
    }
    if (r == NRNG - 1 && tid == 0) rowptr[NN] = bstart[NRNG];
    __syncthreads();
    // pass 2: scatter via LDS cursors
    for (int i = elo + tid; i < ehi; i += 256) {
        unsigned int u = ebuck[i];
        int pos = atomicAdd(&cur[u >> 17], 1);
        esrc[pos] = (int)(u & 0x1FFFFu);
    }
    // layer-0 node transform (hloc unchanged since hist sync)
    const float e = 1.0f + epsp[0];
    for (int idx = tid; idx < nr * 8; idx += 256) {
        int i = idx >> 3, oct = idx & 7;
        unsigned long long hv = hloc[i];
        float cu = (float)((hv >> 21) & 0x1FFFFFull);
        float cv = (float)(hv >> 42);
        unsigned char f = featb[nlo + i];
        float z0 = fmaf(e, (float)(f & 1), cu);
        float z1 = fmaf(e, (float)(f >> 1), cv);
        unsigned int p[4];
        #pragma unroll
        for (int k = 0; k < 4; ++k) {
            int c0 = oct * 8 + 2 * k;
            float o0 = fmaxf(fmaf(z0, w0s[c0],     fmaf(z1, w0s[64 + c0],     b0s[c0])),     0.0f);
            float o1 = fmaxf(fmaf(z0, w0s[c0 + 1], fmaf(z1, w0s[64 + c0 + 1], b0s[c0 + 1])), 0.0f);
            p[k] = pack_bf16(o0, o1);
        }
        ((uint4*)(hout + (size_t)(nlo + i) * 64))[oct] = make_uint4(p[0], p[1], p[2], p[3]);
    }
}

// ---------------- layers 1/2: node-group gather + MFMA GEMV (R20 body) -----
__global__ __launch_bounds__(256) void gin_layer_kernel(
        const int* __restrict__ rowptr, const int* __restrict__ esrc,
        const unsigned short* __restrict__ hin,
        const uint4* __restrict__ wpk, const float* __restrict__ b,
        const float* __restrict__ epsp, unsigned short* __restrict__ hout) {
    __shared__ __align__(16) unsigned char zall[4][2048];   // per-wave z[16][64] bf16
    const int tid = threadIdx.x;
    const int lane = tid & 63;
    const int g = lane >> 3;            // node group 0..7
    const int sub = lane & 7;           // 16B chunk (cols 8*sub..8*sub+7)
    unsigned char* zw = &zall[tid >> 6][0];
    const float ep = 1.0f + epsp[0];

    // preload B fragments from pre-packed global (8 x uint4, L2-hot)
    const int bcol = (lane & 15);
    frag16 Bf[4][2];
    #pragma unroll
    for (int n = 0; n < 4; ++n) {
        #pragma unroll
        for (int t = 0; t < 2; ++t)
            Bf[n][t].u = wpk[(n * 2 + t) * 64 + lane];
    }
    float bj[4];
    #pragma unroll
    for (int n = 0; n < 4; ++n) bj[n] = b[n * 16 + bcol];

    const int wid = (blockIdx.x * blockDim.x + tid) >> 6;
    const int nwaves = (gridDim.x * blockDim.x) >> 6;

    for (int chunk = wid; chunk < NCHUNK; chunk += nwaves) {
        const int cbase_n = chunk * 16;
        // ---- Phase A: two batches of 8 nodes ----
        #pragma unroll
        for (int b8 = 0; b8 < 2; ++b8) {
            int node = cbase_n + b8 * 8 + g;
            int e0 = rowptr[node], e1 = rowptr[node + 1];
            int deg = e1 - e0;
            uint4 ov = ((const uint4*)(hin + (size_t)node * 64))[sub];
            float acc[8];
            #pragma unroll
            for (int c = 0; c < 8; ++c) acc[c] = 0.0f;
            int md = deg;
            md = max(md, __shfl_xor(md, 8));
            md = max(md, __shfl_xor(md, 16));
            md = max(md, __shfl_xor(md, 32));
            #pragma unroll 4
            for (int t = 0; t < md; ++t) {
                int em = max(min(e0 + t, e1 - 1), 0);
                int sraw = esrc[em];
                bool act = (t < deg);
                int s = act ? sraw : node;          // masked: own row (L1-hot)
                uint4 v = ((const uint4*)(hin + (size_t)s * 64))[sub];
                float m = act ? 1.0f : 0.0f;
                acc[0] = fmaf(m, bf_lo(v.x), acc[0]);
                acc[1] = fmaf(m, bf_hi(v.x), acc[1]);
                acc[2] = fmaf(m, bf_lo(v.y), acc[2]);
                acc[3] = fmaf(m, bf_hi(v.y), acc[3]);
                acc[4] = fmaf(m, bf_lo(v.z), acc[4]);
                acc[5] = fmaf(m, bf_hi(v.z), acc[5]);
                acc[6] = fmaf(m, bf_lo(v.w), acc[6]);
                acc[7] = fmaf(m, bf_hi(v.w), acc[7]);
            }
            acc[0] = fmaf(ep, bf_lo(ov.x), acc[0]);
            acc[1] = fmaf(ep, bf_hi(ov.x), acc[1]);
            acc[2] = fmaf(ep, bf_lo(ov.y), acc[2]);
            acc[3] = fmaf(ep, bf_hi(ov.y), acc[3]);
            acc[4] = fmaf(ep, bf_lo(ov.z), acc[4]);
            acc[5] = fmaf(ep, bf_hi(ov.z), acc[5]);
            acc[6] = fmaf(ep, bf_lo(ov.w), acc[6]);
            acc[7] = fmaf(ep, bf_hi(ov.w), acc[7]);
            uint4 pk = make_uint4(pack_bf16(acc[0], acc[1]), pack_bf16(acc[2], acc[3]),
                                  pack_bf16(acc[4], acc[5]), pack_bf16(acc[6], acc[7]));
            int row = b8 * 8 + g;
            *(uint4*)&zw[row * 128 + ((sub ^ g) << 4)] = pk;
        }
        // ---- Phase B: z[16][64] @ W[64][64] via MFMA ----
        const int arow = lane & 15;
        const int hi = lane >> 4;
        frag16 a0, a1;
        a0.u = *(const uint4*)&zw[arow * 128 + (((hi + 0) ^ (lane & 7)) << 4)];
        a1.u = *(const uint4*)&zw[arow * 128 + (((hi + 4) ^ (lane & 7)) << 4)];
        #pragma unroll
        for (int n = 0; n < 4; ++n) {
            f32x4 c = {bj[n], bj[n], bj[n], bj[n]};
            c = __builtin_amdgcn_mfma_f32_16x16x32_bf16(a0.s, Bf[n][0].s, c, 0, 0, 0);
            c = __builtin_amdgcn_mfma_f32_16x16x32_bf16(a1.s, Bf[n][1].s, c, 0, 0, 0);
            #pragma unroll
            for (int q = 0; q < 4; ++q) {
                int rr = hi * 4 + q;
                float v = fmaxf(c[q], 0.0f);
                hout[(size_t)(cbase_n + rr) * 64 + n * 16 + bcol] =
                    (unsigned short)bf16_rne(v);
            }
        }
    }
}

// ---------------- fused mean-pool + scorer: one wave per graph ------------
__global__ __launch_bounds__(256) void pool_scorer_kernel(
        const unsigned short* __restrict__ h, const int* __restrict__ gstart,
        const float* __restrict__ Ws1, const float* __restrict__ bs1,
        const float* __restrict__ Ws2, const float* __restrict__ bs2,
        float* __restrict__ out) {
    int g = blockIdx.x * 4 + (threadIdx.x >> 6);
    int lane = threadIdx.x & 63;
    if (g >= NB) return;
    int s0 = gstart[g], s1 = gstart[g + 1];
    float a0 = 0.0f, a1 = 0.0f, a2 = 0.0f, a3 = 0.0f;
    int i = s0;
    for (; i + 4 <= s1; i += 4) {
        a0 += __uint_as_float((unsigned int)h[(size_t)(i    ) * 64 + lane] << 16);
        a1 += __uint_as_float((unsigned int)h[(size_t)(i + 1) * 64 + lane] << 16);
        a2 += __uint_as_float((unsigned int)h[(size_t)(i + 2) * 64 + lane] << 16);
        a3 += __uint_as_float((unsigned int)h[(size_t)(i + 3) * 64 + lane] << 16);
    }
    for (; i < s1; ++i)
        a0 += __uint_as_float((unsigned int)h[(size_t)i * 64 + lane] << 16);
    float mean = ((a0 + a1) + (a2 + a3)) / fmaxf((float)(s1 - s0), 1.0f);
    float o = bs1[lane];
    #pragma unroll 8
    for (int k = 0; k < 64; ++k)
        o = fmaf(__shfl(mean, k), Ws1[(size_t)k * 64 + lane], o);
    float z = fmaxf(o, 0.0f) * Ws2[lane];
    #pragma unroll
    for (int off = 32; off > 0; off >>= 1) z += __shfl_xor(z, off);
    if (lane == 0) out[g] = 1.0f / (1.0f + expf(-(z + bs2[0])));
}

extern "C" void kernel_launch(void* const* d_in, const int* in_sizes, int n_in,
                              void* d_out, int out_size, void* d_ws, size_t ws_size,
                              hipStream_t stream) {
    const void*  u_flag = d_in[0];
    const void*  v_flag = d_in[1];
    const int*   src    = (const int*)d_in[2];
    const int*   dst    = (const int*)d_in[3];
    const int*   n2g    = (const int*)d_in[4];
    const float* W0     = (const float*)d_in[5];
    const float* b0     = (const float*)d_in[6];
    const float* eps0   = (const float*)d_in[7];
    const float* W1     = (const float*)d_in[8];
    const float* b1     = (const float*)d_in[9];
    const float* eps1   = (const float*)d_in[10];
    const float* W2     = (const float*)d_in[11];
    const float* b2     = (const float*)d_in[12];
    const float* eps2   = (const float*)d_in[13];
    const float* Ws1    = (const float*)d_in[14];
    const float* bs1    = (const float*)d_in[15];
    const float* Ws2    = (const float*)d_in[16];
    const float* bs2    = (const float*)d_in[17];
    float* out = (float*)d_out;

    // ---- workspace layout (int = 4-byte units), non-overlapping ----
    int*    ws     = (int*)d_ws;
    int*    rowptr = ws;                                    // [0,        100001)
    int*    gstart = ws + 100008;                           // [100008,   101033)
    unsigned char* featb = (unsigned char*)(ws + 101036);   // [101036,   126036) 100000 B
    unsigned short* h_a = (unsigned short*)(ws + 126036);   // [126036,   3326036)
    unsigned short* h_b = (unsigned short*)(ws + 3326036);  // [3326036,  6526036)
    int*    esrc   = ws + 6526036;                          // [6526036,  7526036)
    int*    bcnt   = ws + 7526036;                          // [7526036,  7657108) 131072
    int*    bbase  = ws + 7657108;                          // [7657108,  7788180) 131072
    int*    bstart = ws + 7788180;                          // [7788180,  7788437) 257
    int*    btot   = ws + 7788440;                          // [7788440,  7788696) 256
    unsigned int* ebuck = (unsigned int*)(ws + 7788696);    // [7788696,  8788696) NE
    uint4*  wpk1   = (uint4*)(ws + 8788696);                // [8788696,  8790744) 512 uint4
    uint4*  wpk2   = (uint4*)(ws + 8790744);                // [8790744,  8792792)

    const int B256 = 256;

    // fused featb + bucket histogram
    prep_kernel<<<FEATB_BLKS + NBK, B256, 0, stream>>>(u_flag, v_flag, featb,
                                                       n2g, gstart, dst, bcnt);

    // fused bucket totals + W fragment pre-pack
    wsum_kernel<<<NRNG + 2, B256, 0, stream>>>(bcnt, btot, W1, W2, wpk1, wpk2);

    // bucket scan + edge bucketing
    bbase_kernel<<<NRNG, B256, 0, stream>>>(bcnt, btot, bstart, bbase);
    bwrite_kernel<<<NBK, B256, 0, stream>>>(src, dst, bbase, ebuck, NE);

    // fused CSR build + layer-0 transform
    build_kernel<<<NRNG, B256, 0, stream>>>(ebuck, bstart, featb, W0, b0, eps0,
                                            rowptr, esrc, h_a);

    // layers 1/2 (1563 blocks = 6252 waves -> ~1 chunk per wave)
    gin_layer_kernel<<<1563, 256, 0, stream>>>(rowptr, esrc, h_a, wpk1, b1, eps1, h_b);
    gin_layer_kernel<<<1563, 256, 0, stream>>>(rowptr, esrc, h_b, wpk2, b2, eps2, h_a);

    // fused mean-pool + scorer
    pool_scorer_kernel<<<NB / 4, 256, 0, stream>>>(h_a, gstart, Ws1, bs1, Ws2, bs2, out);
}

// Round 23
// 129.467 us; speedup vs baseline: 1.1283x; 1.0176x over previous
//
#include <hip/hip_runtime.h>
#include <hip/hip_bf16.h>
#include <math.h>

#define NN 100000      // nodes
#define NE 1000000     // edges
#define NB 1024        // graphs
#define NCHUNK 6250    // NN/16
#define NRNG 256       // dst ranges
#define RANGE 391      // ceil(NN / NRNG)
#define NBK 512        // blocks for bucketing pass
#define EPB 1954       // edges per bucket-block: 512*1954 >= 1M
#define FEATB_BLKS 392 // 392*256 >= NN

typedef __attribute__((ext_vector_type(8))) short short8v;
typedef __attribute__((ext_vector_type(4))) float f32x4;

union frag16 { uint4 u; short8v s; };

static __device__ __forceinline__ float bf_lo(unsigned int u) {
    return __uint_as_float(u << 16);
}
static __device__ __forceinline__ float bf_hi(unsigned int u) {
    return __uint_as_float(u & 0xffff0000u);
}
static __device__ __forceinline__ unsigned int bf16_rne(float f) {
    unsigned int u = __float_as_uint(f);
    return (u + 0x7fffu + ((u >> 16) & 1u)) >> 16;
}
static __device__ __forceinline__ unsigned int pack_bf16(float a, float b) {
    return bf16_rne(a) | (bf16_rne(b) << 16);
}

// ---------------------------------------------------------------------------
// Fused: featb build (blocks < FEATB_BLKS) + edge bucket histogram (rest).
__global__ __launch_bounds__(256) void prep_kernel(
        const void* __restrict__ u, const void* __restrict__ v,
        unsigned char* __restrict__ featb,
        const int* __restrict__ n2g, int* __restrict__ gstart,
        const int* __restrict__ dst, int* __restrict__ bcnt) {
    __shared__ int sh[NRNG];
    const int tid = threadIdx.x;
    if (blockIdx.x < FEATB_BLKS) {
        // ---- featb path (+inlined bool-layout detection, fused boundary) ----
        int c;
        {
            const unsigned char* p = (const unsigned char*)u + tid * 4;
            c = (p[0] != 0) + (p[1] != 0) + (p[2] != 0) + (p[3] != 0);
        }
        #pragma unroll
        for (int off = 32; off > 0; off >>= 1) c += __shfl_xor(c, off);
        if (tid == 0) sh[0] = 0;
        __syncthreads();
        if ((tid & 63) == 0) atomicAdd(&sh[0], c);
        __syncthreads();
        bool is_u8 = (4 * sh[0] > 1024);   // u8: ~512 nonzero; i32: ~128
        int i = blockIdx.x * 256 + tid;
        if (i >= NN) return;
        unsigned char fu, fv;
        if (is_u8) {
            fu = ((const unsigned char*)u)[i] ? 1 : 0;
            fv = ((const unsigned char*)v)[i] ? 1 : 0;
        } else {
            fu = ((const int*)u)[i] ? 1 : 0;
            fv = ((const int*)v)[i] ? 1 : 0;
        }
        featb[i] = fu | (fv << 1);
        int g = n2g[i];
        if (i == 0) {
            gstart[g] = 0;
            gstart[NB] = NN;
        } else if (n2g[i - 1] != g) {
            gstart[g] = i;
        }
    } else {
        // ---- bcount path ----
        const int blk = blockIdx.x - FEATB_BLKS;
        sh[tid] = 0;
        __syncthreads();
        const int lo = blk * EPB, hi = min(NE, lo + EPB);
        for (int i = lo + tid; i < hi; i += 256)
            atomicAdd(&sh[dst[i] / RANGE], 1);
        __syncthreads();
        bcnt[tid * NBK + blk] = sh[tid];
    }
}

// Fused: per-bucket totals (blocks < NRNG) + W1/W2 fragment pre-pack (2 blocks).
__global__ __launch_bounds__(256) void wsum_kernel(
        const int* __restrict__ bcnt, int* __restrict__ btot,
        const float* __restrict__ W1, const float* __restrict__ W2,
        uint4* __restrict__ wpk1, uint4* __restrict__ wpk2) {
    __shared__ int s[4];
    const int tid = threadIdx.x;
    if (blockIdx.x < NRNG) {
        const int b = blockIdx.x;
        int c = bcnt[b * NBK + tid] + bcnt[b * NBK + 256 + tid];
        #pragma unroll
        for (int off = 32; off > 0; off >>= 1) c += __shfl_xor(c, off);
        if ((tid & 63) == 0) s[tid >> 6] = c;
        __syncthreads();
        if (tid == 0) btot[b] = s[0] + s[1] + s[2] + s[3];
    } else {
        if (tid >= 64) return;
        const float* W = (blockIdx.x == NRNG) ? W1 : W2;
        uint4* wpk = (blockIdx.x == NRNG) ? wpk1 : wpk2;
        const int lane = tid;
        const int bcol = lane & 15;
        const int krow = (lane >> 4) * 8;
        #pragma unroll
        for (int n = 0; n < 4; ++n) {
            #pragma unroll
            for (int t = 0; t < 2; ++t) {
                unsigned int p[4];
                #pragma unroll
                for (int jj = 0; jj < 4; ++jj) {
                    int k0 = t * 32 + krow + 2 * jj;
                    float w0 = W[(size_t)k0 * 64 + n * 16 + bcol];
                    float w1 = W[(size_t)(k0 + 1) * 64 + n * 16 + bcol];
                    p[jj] = pack_bf16(w0, w1);
                }
                wpk[(n * 2 + t) * 64 + lane] = make_uint4(p[0], p[1], p[2], p[3]);
            }
        }
    }
}

// stage 2 (fused): bucket-total scan (block 0 writes bstart) + per-bucket
// exclusive scan of the 512 per-block counts -> bbase.
__global__ __launch_bounds__(256) void bbase_kernel(const int* __restrict__ bcnt,
                                                    const int* __restrict__ btot,
                                                    int* __restrict__ bstart,
                                                    int* __restrict__ bbase) {
    __shared__ int s[256];
    const int b = blockIdx.x, tid = threadIdx.x;
    int v = btot[tid];
    s[tid] = v;
    __syncthreads();
    for (int off = 1; off < 256; off <<= 1) {
        int t = (tid >= off) ? s[tid - off] : 0;
        __syncthreads();
        s[tid] += t;
        __syncthreads();
    }
    if (b == 0) {
        bstart[tid] = s[tid] - v;
        if (tid == 255) bstart[NRNG] = s[tid];
    }
    const int exb = s[b] - btot[b];            // exclusive start of bucket b
    __syncthreads();
    int2 c = ((const int2*)(bcnt + b * NBK))[tid];
    int lsum = c.x + c.y;
    s[tid] = lsum;
    __syncthreads();
    for (int off = 1; off < 256; off <<= 1) {
        int t = (tid >= off) ? s[tid - off] : 0;
        __syncthreads();
        s[tid] += t;
        __syncthreads();
    }
    int run = exb + s[tid] - lsum;
    ((int2*)(bbase + b * NBK))[tid] = make_int2(run, run + c.x);
}

__global__ __launch_bounds__(256) void bwrite_kernel(const int* __restrict__ src,
                                                     const int* __restrict__ dst,
                                                     const int* __restrict__ bbase,
                                                     unsigned int* __restrict__ ebuck, int e) {
    __shared__ int cur[NRNG];
    const int blk = blockIdx.x;
    cur[threadIdx.x] = bbase[threadIdx.x * NBK + blk];
    __syncthreads();
    const int lo = blk * EPB, hi = min(e, lo + EPB);
    for (int i = lo + threadIdx.x; i < hi; i += 256) {
        int d = dst[i];
        int b = d / RANGE;
        int dloc = d - b * RANGE;                  // < 391 < 2^9
        int pos = atomicAdd(&cur[b], 1);
        ebuck[pos] = (unsigned int)src[i] | ((unsigned int)dloc << 17);
    }
}

// ---------------- fused CSR build + layer-0 node transform ------------------
__global__ __launch_bounds__(256) void build_kernel(
        const unsigned int* __restrict__ ebuck, const int* __restrict__ bstart,
        const unsigned char* __restrict__ featb,
        const float* __restrict__ W0, const float* __restrict__ b0,
        const float* __restrict__ epsp,
        int* __restrict__ rowptr, int* __restrict__ esrc,
        unsigned short* __restrict__ hout) {
    __shared__ unsigned long long hloc[RANGE];     // 3128 B
    __shared__ int cur[RANGE];                     // 1564 B
    __shared__ int sscan[256];
    __shared__ float w0s[128];
    __shared__ float b0s[64];
    const int r = blockIdx.x, tid = threadIdx.x;
    const int nlo = r * RANGE;
    const int nr = min(NN, nlo + RANGE) - nlo;
    for (int i = tid; i < nr; i += 256) hloc[i] = 0ull;
    if (tid < 128) w0s[tid] = W0[tid];
    if (tid >= 128 && tid < 192) b0s[tid - 128] = b0[tid - 128];
    __syncthreads();
    const int elo = bstart[r], ehi = bstart[r + 1];
    // pass 1: LDS histogram
    for (int i = elo + tid; i < ehi; i += 256) {
        unsigned int u = ebuck[i];
        unsigned char f = featb[u & 0x1FFFFu];
        unsigned long long inc = 1ull
            | ((unsigned long long)(f & 1) << 21)
            | ((unsigned long long)(f >> 1) << 42);
        atomicAdd(&hloc[u >> 17], inc);
    }
    __syncthreads();
    // in-LDS exclusive scan of degrees (2 slots per thread)
    const int base = tid * 2;
    int ldeg[2];
    int lsum = 0;
    #pragma unroll
    for (int j = 0; j < 2; ++j) {
        int i = base + j;
        ldeg[j] = (i < nr) ? (int)(hloc[i] & 0x1FFFFFull) : 0;
        lsum += ldeg[j];
    }
    sscan[tid] = lsum;
    __syncthreads();
    for (int off = 1; off < 256; off <<= 1) {
        int t = (tid >= off) ? sscan[tid - off] : 0;
        __syncthreads();
        sscan[tid] += t;
        __syncthreads();
    }
    int run = elo + sscan[tid] - lsum;
    #pragma unroll
    for (int j = 0; j < 2; ++j) {
        int i = base + j;
        if (i < nr) {
            rowptr[nlo + i] = run;
            cur[i] = run;
            run += ldeg[j];
        }
    }
    if (r == NRNG - 1 && tid == 0) rowptr[NN] = bstart[NRNG];
    __syncthreads();
    // pass 2: scatter via LDS cursors
    for (int i = elo + tid; i < ehi; i += 256) {
        unsigned int u = ebuck[i];
        int pos = atomicAdd(&cur[u >> 17], 1);
        esrc[pos] = (int)(u & 0x1FFFFu);
    }
    // layer-0 node transform (hloc unchanged since hist sync)
    const float e = 1.0f + epsp[0];
    for (int idx = tid; idx < nr * 8; idx += 256) {
        int i = idx >> 3, oct = idx & 7;
        unsigned long long hv = hloc[i];
        float cu = (float)((hv >> 21) & 0x1FFFFFull);
        float cv = (float)(hv >> 42);
        unsigned char f = featb[nlo + i];
        float z0 = fmaf(e, (float)(f & 1), cu);
        float z1 = fmaf(e, (float)(f >> 1), cv);
        unsigned int p[4];
        #pragma unroll
        for (int k = 0; k < 4; ++k) {
            int c0 = oct * 8 + 2 * k;
            float o0 = fmaxf(fmaf(z0, w0s[c0],     fmaf(z1, w0s[64 + c0],     b0s[c0])),     0.0f);
            float o1 = fmaxf(fmaf(z0, w0s[c0 + 1], fmaf(z1, w0s[64 + c0 + 1], b0s[c0 + 1])), 0.0f);
            p[k] = pack_bf16(o0, o1);
        }
        ((uint4*)(hout + (size_t)(nlo + i) * 64))[oct] = make_uint4(p[0], p[1], p[2], p[3]);
    }
}

// ---------------- layers 1/2: batched-MLP gather + MFMA GEMV ---------------
// Per 8 edges: load 8 esrc (independent) -> 8 row-gathers (independent) ->
// 64 FMAs. __launch_bounds__(256,2) lifts the VGPR cap so all 8 gathers
// stay in flight (R19's unroll-8 failed because VGPR was capped at 56).
__global__ __launch_bounds__(256, 2) void gin_layer_kernel(
        const int* __restrict__ rowptr, const int* __restrict__ esrc,
        const unsigned short* __restrict__ hin,
        const uint4* __restrict__ wpk, const float* __restrict__ b,
        const float* __restrict__ epsp, unsigned short* __restrict__ hout) {
    __shared__ __align__(16) unsigned char zall[4][2048];   // per-wave z[16][64] bf16
    const int tid = threadIdx.x;
    const int lane = tid & 63;
    const int g = lane >> 3;            // node group 0..7
    const int sub = lane & 7;           // 16B chunk (cols 8*sub..8*sub+7)
    unsigned char* zw = &zall[tid >> 6][0];
    const float ep = 1.0f + epsp[0];

    // preload B fragments from pre-packed global (8 x uint4, L2-hot)
    const int bcol = (lane & 15);
    frag16 Bf[4][2];
    #pragma unroll
    for (int n = 0; n < 4; ++n) {
        #pragma unroll
        for (int t = 0; t < 2; ++t)
            Bf[n][t].u = wpk[(n * 2 + t) * 64 + lane];
    }
    float bj[4];
    #pragma unroll
    for (int n = 0; n < 4; ++n) bj[n] = b[n * 16 + bcol];

    const int wid = (blockIdx.x * blockDim.x + tid) >> 6;
    const int nwaves = (gridDim.x * blockDim.x) >> 6;

    for (int chunk = wid; chunk < NCHUNK; chunk += nwaves) {
        const int cbase_n = chunk * 16;
        // ---- Phase A: two batches of 8 nodes ----
        #pragma unroll
        for (int b8 = 0; b8 < 2; ++b8) {
            int node = cbase_n + b8 * 8 + g;
            int e0 = rowptr[node], e1 = rowptr[node + 1];
            int deg = e1 - e0;
            uint4 ov = ((const uint4*)(hin + (size_t)node * 64))[sub];
            float acc[8];
            #pragma unroll
            for (int c = 0; c < 8; ++c) acc[c] = 0.0f;
            int md = deg;
            md = max(md, __shfl_xor(md, 8));
            md = max(md, __shfl_xor(md, 16));
            md = max(md, __shfl_xor(md, 32));
            // batched MLP: 8 esrc loads -> 8 gathers -> 64 fmas
            for (int tb = 0; tb < md; tb += 8) {
                int se[8];
                #pragma unroll
                for (int tt = 0; tt < 8; ++tt) {
                    int em = max(min(e0 + tb + tt, e1 - 1), 0);
                    se[tt] = esrc[em];
                }
                uint4 vv[8];
                #pragma unroll
                for (int tt = 0; tt < 8; ++tt) {
                    bool act = (tb + tt < deg);
                    int s = act ? se[tt] : node;    // masked: own row (L1-hot)
                    vv[tt] = ((const uint4*)(hin + (size_t)s * 64))[sub];
                }
                #pragma unroll
                for (int tt = 0; tt < 8; ++tt) {
                    float m = (tb + tt < deg) ? 1.0f : 0.0f;
                    acc[0] = fmaf(m, bf_lo(vv[tt].x), acc[0]);
                    acc[1] = fmaf(m, bf_hi(vv[tt].x), acc[1]);
                    acc[2] = fmaf(m, bf_lo(vv[tt].y), acc[2]);
                    acc[3] = fmaf(m, bf_hi(vv[tt].y), acc[3]);
                    acc[4] = fmaf(m, bf_lo(vv[tt].z), acc[4]);
                    acc[5] = fmaf(m, bf_hi(vv[tt].z), acc[5]);
                    acc[6] = fmaf(m, bf_lo(vv[tt].w), acc[6]);
                    acc[7] = fmaf(m, bf_hi(vv[tt].w), acc[7]);
                }
            }
            acc[0] = fmaf(ep, bf_lo(ov.x), acc[0]);
            acc[1] = fmaf(ep, bf_hi(ov.x), acc[1]);
            acc[2] = fmaf(ep, bf_lo(ov.y), acc[2]);
            acc[3] = fmaf(ep, bf_hi(ov.y), acc[3]);
            acc[4] = fmaf(ep, bf_lo(ov.z), acc[4]);
            acc[5] = fmaf(ep, bf_hi(ov.z), acc[5]);
            acc[6] = fmaf(ep, bf_lo(ov.w), acc[6]);
            acc[7] = fmaf(ep, bf_hi(ov.w), acc[7]);
            uint4 pk = make_uint4(pack_bf16(acc[0], acc[1]), pack_bf16(acc[2], acc[3]),
                                  pack_bf16(acc[4], acc[5]), pack_bf16(acc[6], acc[7]));
            int row = b8 * 8 + g;
            *(uint4*)&zw[row * 128 + ((sub ^ g) << 4)] = pk;
        }
        // ---- Phase B: z[16][64] @ W[64][64] via MFMA ----
        const int arow = lane & 15;
        const int hi = lane >> 4;
        frag16 a0, a1;
        a0.u = *(const uint4*)&zw[arow * 128 + (((hi + 0) ^ (lane & 7)) << 4)];
        a1.u = *(const uint4*)&zw[arow * 128 + (((hi + 4) ^ (lane & 7)) << 4)];
        #pragma unroll
        for (int n = 0; n < 4; ++n) {
            f32x4 c = {bj[n], bj[n], bj[n], bj[n]};
            c = __builtin_amdgcn_mfma_f32_16x16x32_bf16(a0.s, Bf[n][0].s, c, 0, 0, 0);
            c = __builtin_amdgcn_mfma_f32_16x16x32_bf16(a1.s, Bf[n][1].s, c, 0, 0, 0);
            #pragma unroll
            for (int q = 0; q < 4; ++q) {
                int rr = hi * 4 + q;
                float v = fmaxf(c[q], 0.0f);
                hout[(size_t)(cbase_n + rr) * 64 + n * 16 + bcol] =
                    (unsigned short)bf16_rne(v);
            }
        }
    }
}

// ---------------- fused mean-pool + scorer: one wave per graph ------------
__global__ __launch_bounds__(256) void pool_scorer_kernel(
        const unsigned short* __restrict__ h, const int* __restrict__ gstart,
        const float* __restrict__ Ws1, const float* __restrict__ bs1,
        const float* __restrict__ Ws2, const float* __restrict__ bs2,
        float* __restrict__ out) {
    int g = blockIdx.x * 4 + (threadIdx.x >> 6);
    int lane = threadIdx.x & 63;
    if (g >= NB) return;
    int s0 = gstart[g], s1 = gstart[g + 1];
    float a0 = 0.0f, a1 = 0.0f, a2 = 0.0f, a3 = 0.0f;
    int i = s0;
    for (; i + 4 <= s1; i += 4) {
        a0 += __uint_as_float((unsigned int)h[(size_t)(i    ) * 64 + lane] << 16);
        a1 += __uint_as_float((unsigned int)h[(size_t)(i + 1) * 64 + lane] << 16);
        a2 += __uint_as_float((unsigned int)h[(size_t)(i + 2) * 64 + lane] << 16);
        a3 += __uint_as_float((unsigned int)h[(size_t)(i + 3) * 64 + lane] << 16);
    }
    for (; i < s1; ++i)
        a0 += __uint_as_float((unsigned int)h[(size_t)i * 64 + lane] << 16);
    float mean = ((a0 + a1) + (a2 + a3)) / fmaxf((float)(s1 - s0), 1.0f);
    float o = bs1[lane];
    #pragma unroll 8
    for (int k = 0; k < 64; ++k)
        o = fmaf(__shfl(mean, k), Ws1[(size_t)k * 64 + lane], o);
    float z = fmaxf(o, 0.0f) * Ws2[lane];
    #pragma unroll
    for (int off = 32; off > 0; off >>= 1) z += __shfl_xor(z, off);
    if (lane == 0) out[g] = 1.0f / (1.0f + expf(-(z + bs2[0])));
}

extern "C" void kernel_launch(void* const* d_in, const int* in_sizes, int n_in,
                              void* d_out, int out_size, void* d_ws, size_t ws_size,
                              hipStream_t stream) {
    const void*  u_flag = d_in[0];
    const void*  v_flag = d_in[1];
    const int*   src    = (const int*)d_in[2];
    const int*   dst    = (const int*)d_in[3];
    const int*   n2g    = (const int*)d_in[4];
    const float* W0     = (const float*)d_in[5];
    const float* b0     = (const float*)d_in[6];
    const float* eps0   = (const float*)d_in[7];
    const float* W1     = (const float*)d_in[8];
    const float* b1     = (const float*)d_in[9];
    const float* eps1   = (const float*)d_in[10];
    const float* W2     = (const float*)d_in[11];
    const float* b2     = (const float*)d_in[12];
    const float* eps2   = (const float*)d_in[13];
    const float* Ws1    = (const float*)d_in[14];
    const float* bs1    = (const float*)d_in[15];
    const float* Ws2    = (const float*)d_in[16];
    const float* bs2    = (const float*)d_in[17];
    float* out = (float*)d_out;

    // ---- workspace layout (int = 4-byte units), non-overlapping ----
    int*    ws     = (int*)d_ws;
    int*    rowptr = ws;                                    // [0,        100001)
    int*    gstart = ws + 100008;                           // [100008,   101033)
    unsigned char* featb = (unsigned char*)(ws + 101036);   // [101036,   126036) 100000 B
    unsigned short* h_a = (unsigned short*)(ws + 126036);   // [126036,   3326036)
    unsigned short* h_b = (unsigned short*)(ws + 3326036);  // [3326036,  6526036)
    int*    esrc   = ws + 6526036;                          // [6526036,  7526036)
    int*    bcnt   = ws + 7526036;                          // [7526036,  7657108) 131072
    int*    bbase  = ws + 7657108;                          // [7657108,  7788180) 131072
    int*    bstart = ws + 7788180;                          // [7788180,  7788437) 257
    int*    btot   = ws + 7788440;                          // [7788440,  7788696) 256
    unsigned int* ebuck = (unsigned int*)(ws + 7788696);    // [7788696,  8788696) NE
    uint4*  wpk1   = (uint4*)(ws + 8788696);                // [8788696,  8790744) 512 uint4
    uint4*  wpk2   = (uint4*)(ws + 8790744);                // [8790744,  8792792)

    const int B256 = 256;

    // fused featb + bucket histogram
    prep_kernel<<<FEATB_BLKS + NBK, B256, 0, stream>>>(u_flag, v_flag, featb,
                                                       n2g, gstart, dst, bcnt);

    // fused bucket totals + W fragment pre-pack
    wsum_kernel<<<NRNG + 2, B256, 0, stream>>>(bcnt, btot, W1, W2, wpk1, wpk2);

    // bucket scan + edge bucketing
    bbase_kernel<<<NRNG, B256, 0, stream>>>(bcnt, btot, bstart, bbase);
    bwrite_kernel<<<NBK, B256, 0, stream>>>(src, dst, bbase, ebuck, NE);

    // fused CSR build + layer-0 transform
    build_kernel<<<NRNG, B256, 0, stream>>>(ebuck, bstart, featb, W0, b0, eps0,
                                            rowptr, esrc, h_a);

    // layers 1/2 (1563 blocks = 6252 waves -> ~1 chunk per wave)
    gin_layer_kernel<<<1563, 256, 0, stream>>>(rowptr, esrc, h_a, wpk1, b1, eps1, h_b);
    gin_layer_kernel<<<1563, 256, 0, stream>>>(rowptr, esrc, h_b, wpk2, b2, eps2, h_a);

    // fused mean-pool + scorer
    pool_scorer_kernel<<<NB / 4, 256, 0, stream>>>(h_a, gstart, Ws1, bs1, Ws2, bs2, out);
}